// Round 19
// baseline (167.684 us; speedup 1.0000x reference)
//
#include <hip/hip_runtime.h>
#include <hip/hip_bf16.h>
#include <cstdint>

// ---------------------------------------------------------------------------
// TagProjector fused kernel (R19):
//   flat = tab[clamp(ids,0)]                  [51200, 512]  (gather, f32->bf16)
//   h    = gelu_tanh(flat @ w1 + b1)          [51200, 1024] (bf16 MFMA)
//   y    = h @ w2 + b2                        [51200, 256]  (bf16 MFMA, reg acc)
//   out  = mask ? 0 : y / max(||y||, 1e-12)   [51200, 256]  f32
//
// R19 = R14 structure (3-slot depth-2 W rotations, wr2 hoist, 1 barrier per
// chunk, balanced 256-block grid) with MT 64->48 (RT=3) + A-tile DOUBLE
// BUFFER + pipelined gather: tile t+1's rows are loaded (4 float4/thread per
// chunk, issued at GEMM1(c) top -> full-chunk latency cover) and written to
// A[next] right after chunk c's barrier (whose vmcnt drain guarantees
// arrival). Kills the ~15-25us serial gather phase. Side effect: acc arrays
// 32->24 regs each => GEMM1 peak ~118 < the hard 128 cap => spill ~dies.
// LDS: A dbuf 96K + H dbuf 48K + Ns/Rid 2K = 146KB (1 block/CU).
// ---------------------------------------------------------------------------

typedef __bf16 bf16;
typedef bf16  bf16x8 __attribute__((ext_vector_type(8)));
typedef bf16  bf16x4 __attribute__((ext_vector_type(4)));
typedef float f32x4  __attribute__((ext_vector_type(4)));

#define D_IN    512
#define D_HID   1024
#define D_OUT   256
#define MT      48        // rows per full tile (RT=3)
#define RPB     200       // rows per block (51200 / 256)
#define NBLK    256
#define CHUNK   256       // N1 chunk width
#define NCH     4         // D_HID / CHUNK
#define NKS1    16        // D_IN / 32
#define NKS2C   8         // CHUNK / 32
#define THREADS 512

// LDS layout (bytes)
#define A_TILE   (48 * 512 * 2)             // 49152 per buffer
#define OFF_A    0                          // 2 * 49152 = 98304
#define OFF_H    98304                      // 2 * 48*256*2 = 49152
#define OFF_NS   (98304 + 49152)            // 48*8*4 = 1536
#define OFF_RID  (OFF_NS + 1536)            // 2*48*4 = 384
#define LDS_TOTAL (OFF_RID + 384)           // 149376 -> 1 block/CU

// ws layout: W1f bf16 [64 ct][16 ks][64 lane][8]  (1 MB)
//            W2f bf16 [16 ct][32 ks][64 lane][8]  (512 KB)
#define W1F_ELEMS (64 * 16 * 64 * 8)   // 524288

__device__ __forceinline__ float gelu_tanh(float x) {
  // jax.nn.gelu default (approximate=True): 0.5x(1+tanh(u)) == x*sigmoid(2u)
  float u = 0.7978845608028654f * (x + 0.044715f * x * x * x);
  return x * __builtin_amdgcn_rcpf(1.0f + __expf(-2.0f * u));
}

// ------------------- prep: f32 weights -> bf16 fragment order -------------------
__global__ void prep_weights(const float* __restrict__ w1, const float* __restrict__ w2,
                             bf16* __restrict__ w1f, bf16* __restrict__ w2f) {
  const int t = blockIdx.x * blockDim.x + threadIdx.x;
  if (t < 65536) {                       // W1: 64 ct * 16 ks * 64 lanes
    const int l  = t & 63;
    const int ks = (t >> 6) & 15;
    const int ct = t >> 10;
    const int col   = ct * 16 + (l & 15);
    const int kbase = ks * 32 + (l >> 4) * 8;
    bf16x8 o;
#pragma unroll
    for (int j = 0; j < 8; ++j) o[j] = (bf16)w1[(size_t)(kbase + j) * D_HID + col];
    *(bf16x8*)(w1f + (size_t)t * 8) = o;
  } else if (t < 65536 + 32768) {        // W2: 16 ct * 32 ks * 64 lanes
    const int t2 = t - 65536;
    const int l   = t2 & 63;
    const int ks2 = (t2 >> 6) & 31;
    const int ct2 = t2 >> 11;
    const int col   = ct2 * 16 + (l & 15);
    const int kbase = ks2 * 32 + (l >> 4) * 8;
    bf16x8 o;
#pragma unroll
    for (int j = 0; j < 8; ++j) o[j] = (bf16)w2[(size_t)(kbase + j) * D_OUT + col];
    *(bf16x8*)(w2f + (size_t)t2 * 8) = o;
  }
}

// ------------- serial gather (prologue only): NR rows, RVv valid -------------
__device__ __forceinline__ void gather_rows(
    const float* __restrict__ tab, const int* __restrict__ ids,
    bf16* Adst, int* RidDst, int row0, int NR, int RVv, int tid) {
  if (tid < NR * 8) {
    const int row = tid >> 3;
    const int q   = tid & 7;
    const int id  = (row < RVv) ? ids[row0 + row] : -1;
    if (q == 0) RidDst[row] = id;
    const float* src = tab + (size_t)(id < 0 ? 0 : id) * D_IN;
#pragma unroll
    for (int i = 0; i < 16; ++i) {
      const int c4 = i * 32 + q * 4;
      const float4 v = *(const float4*)(src + c4);
      bf16x4 b;
      b[0] = (bf16)v.x; b[1] = (bf16)v.y; b[2] = (bf16)v.z; b[3] = (bf16)v.w;
      *(bf16x4*)&Adst[row * 512 + (c4 ^ ((row & 15) << 3))] = b;
    }
  }
}

// ----------------------------- tile body ---------------------------------
// RT: 16-row sub-tiles this tile (3 = full 48-row tile, 1 = 16-row tail)
// RV: valid rows (stores masked beyond)
// PF: prefetch next tile's A?  NRN: next-tile rows (48 or 16)  RVN: next valid
template<int RT, int RV, bool PF, int NRN, int RVN>
__device__ __forceinline__ void process_tile(
    const float* __restrict__ tab, const int* __restrict__ ids,
    const bf16* __restrict__ w1f, const bf16* __restrict__ w2f,
    const float* __restrict__ b1, const float* __restrict__ b2,
    float* __restrict__ out,
    bf16* Ab, bf16* Hb, float* Ns, int* Rid,
    int row0, int nxt_row0, int buf,
    int tid, int w, int l, int lg, int lc) {

  bf16* Acur = Ab + buf * (MT * 512);
  bf16* Anxt = Ab + (buf ^ 1) * (MT * 512);
  int*  RidC = Rid + buf * MT;
  int*  RidN = Rid + (buf ^ 1) * MT;

  __syncthreads();  // prev tile fully done: A[cur]/Rid[cur] visible, A[nxt] free

  // next-tile ids for the pipelined gather (each gather thread loads its own)
  int nrow = 0, q = 0;
  const float* nsrc = tab;
  bool act = false;
  if (PF) {
    nrow = tid >> 3;  q = tid & 7;
    act  = tid < NRN * 8;
    if (act) {
      const int nid = (nrow < RVN) ? ids[nxt_row0 + nrow] : -1;
      if (q == 0) RidN[nrow] = nid;
      nsrc = tab + (size_t)(nid < 0 ? 0 : nid) * D_IN;
    }
  }

  // persistent GEMM2 accumulators: rows g*16+lg*4+r, cols (w*2+t)*16+lc
  f32x4 acc2[RT][2];
#pragma unroll
  for (int g = 0; g < RT; ++g)
#pragma unroll
    for (int t = 0; t < 2; ++t) acc2[g][t] = (f32x4){0.f, 0.f, 0.f, 0.f};

  for (int c = 0; c < NCH; ++c) {
    bf16* Hs = Hb + (c & 1) * (MT * CHUNK);

    // ---- issue gather group c for tile t+1 (covered by whole GEMM1 chunk) ----
    float4 st0, st1, st2, st3;
    if (act) {
      st0 = *(const float4*)(nsrc + (c * 4 + 0) * 32 + q * 4);
      st1 = *(const float4*)(nsrc + (c * 4 + 1) * 32 + q * 4);
      st2 = *(const float4*)(nsrc + (c * 4 + 2) * 32 + q * 4);
      st3 = *(const float4*)(nsrc + (c * 4 + 3) * 32 + q * 4);
    }

    // ===== GEMM1: h_chunk = A @ W1[:, c*256:+256] (3-slot, depth-2) =====
    f32x4 acc1[RT][2];
#pragma unroll
    for (int g = 0; g < RT; ++g)
#pragma unroll
      for (int t = 0; t < 2; ++t) acc1[g][t] = (f32x4){0.f, 0.f, 0.f, 0.f};

    // fragment: ((ct*16 + ks)*64 + l)*8, ct = c*16 + w*2 + t
    const bf16* w1p = w1f + (((size_t)(c * 16 + w * 2) * 16) * 64 + l) * 8;
    const bf16* w2p = w2f + (((size_t)(w * 2) * 32 + c * 8) * 64 + l) * 8;
    bf16x8 wr1[3][2];
#pragma unroll
    for (int pf = 0; pf < 2; ++pf)
#pragma unroll
      for (int t = 0; t < 2; ++t)
        wr1[pf][t] = *(const bf16x8*)(w1p + (size_t)t * 8192 + (size_t)pf * 512);

#pragma unroll
    for (int ks = 0; ks < NKS1; ++ks) {
      if (ks + 2 < NKS1) {
#pragma unroll
        for (int t = 0; t < 2; ++t)
          wr1[(ks + 2) % 3][t] =
              *(const bf16x8*)(w1p + (size_t)t * 8192 + (size_t)(ks + 2) * 512);
      }
      bf16x8 af[RT];
#pragma unroll
      for (int g = 0; g < RT; ++g) {
        const int e = ks * 32 + lg * 8;
        af[g] = *(const bf16x8*)&Acur[(g * 16 + lc) * 512 + (e ^ (lc << 3))];
      }
#pragma unroll
      for (int t = 0; t < 2; ++t)
#pragma unroll
        for (int g = 0; g < RT; ++g)
          acc1[g][t] = __builtin_amdgcn_mfma_f32_16x16x32_bf16(
              af[g], wr1[ks % 3][t], acc1[g][t], 0, 0, 0);
    }

    // ---- GEMM2's initial W2 prefetch issued EARLY (independent of H) ----
    bf16x8 wr2[3][2];
#pragma unroll
    for (int pf = 0; pf < 2; ++pf)
#pragma unroll
      for (int t = 0; t < 2; ++t)
        wr2[pf][t] = *(const bf16x8*)(w2p + (size_t)t * 16384 + (size_t)pf * 512);

    // ---- bias + GELU -> bf16 h chunk in LDS (swizzled, double-buffered) ----
#pragma unroll
    for (int t = 0; t < 2; ++t) {
      const int pos    = w * 2 + t;
      const float bias = b1[c * CHUNK + pos * 16 + lc];
#pragma unroll
      for (int g = 0; g < RT; ++g) {
#pragma unroll
        for (int r = 0; r < 4; ++r) {
          const float x  = acc1[g][t][r] + bias;
          const float hx = gelu_tanh(x);
          const int row  = g * 16 + lg * 4 + r;
          const int e    = pos * 16 + lc;
          Hs[row * 256 + (e ^ ((row & 15) << 3))] = (bf16)hx;
        }
      }
    }
    __syncthreads();   // h visible; barrier's vmcnt drain completed st0..st3

    // ---- write gather group c to A[nxt] (loads guaranteed complete) ----
    if (act) {
#pragma unroll
      for (int j = 0; j < 4; ++j) {
        const float4 v = (j == 0) ? st0 : (j == 1) ? st1 : (j == 2) ? st2 : st3;
        const int c4 = (c * 4 + j) * 32 + q * 4;
        bf16x4 b;
        b[0] = (bf16)v.x; b[1] = (bf16)v.y; b[2] = (bf16)v.z; b[3] = (bf16)v.w;
        *(bf16x4*)&Anxt[nrow * 512 + (c4 ^ ((nrow & 15) << 3))] = b;
      }
    }

    // ===== GEMM2: y += h_chunk @ W2[c*256:+256, :] (3-slot, depth-2) =====
#pragma unroll
    for (int s2 = 0; s2 < NKS2C; ++s2) {
      if (s2 + 2 < NKS2C) {
#pragma unroll
        for (int t = 0; t < 2; ++t)
          wr2[(s2 + 2) % 3][t] =
              *(const bf16x8*)(w2p + (size_t)t * 16384 + (size_t)(s2 + 2) * 512);
      }
      bf16x8 hf[RT];
#pragma unroll
      for (int g = 0; g < RT; ++g) {
        const int e = s2 * 32 + lg * 8;
        hf[g] = *(const bf16x8*)&Hs[(g * 16 + lc) * 256 + (e ^ (lc << 3))];
      }
#pragma unroll
      for (int t = 0; t < 2; ++t)
#pragma unroll
        for (int g = 0; g < RT; ++g)
          acc2[g][t] = __builtin_amdgcn_mfma_f32_16x16x32_bf16(
              hf[g], wr2[s2 % 3][t], acc2[g][t], 0, 0, 0);
    }
  }

  // ---- epilogue: +b2, row L2-norm, pad mask, store ----
  float bias2[2];
  bias2[0] = b2[(w * 2 + 0) * 16 + lc];
  bias2[1] = b2[(w * 2 + 1) * 16 + lc];

  float ssq[RT][4];
#pragma unroll
  for (int g = 0; g < RT; ++g)
#pragma unroll
    for (int r = 0; r < 4; ++r) ssq[g][r] = 0.f;

#pragma unroll
  for (int t = 0; t < 2; ++t)
#pragma unroll
    for (int g = 0; g < RT; ++g)
#pragma unroll
      for (int r = 0; r < 4; ++r) {
        const float v = acc2[g][t][r] + bias2[t];
        ssq[g][r] += v * v;
      }

#pragma unroll
  for (int g = 0; g < RT; ++g)
#pragma unroll
    for (int r = 0; r < 4; ++r) {
      float s = ssq[g][r];
      s += __shfl_xor(s, 1);
      s += __shfl_xor(s, 2);
      s += __shfl_xor(s, 4);
      s += __shfl_xor(s, 8);
      ssq[g][r] = s;   // per-wave partial (32 of 256 cols)
    }
  if (lc == 0) {
#pragma unroll
    for (int g = 0; g < RT; ++g)
#pragma unroll
      for (int r = 0; r < 4; ++r)
        Ns[(g * 16 + lg * 4 + r) * 8 + w] = ssq[g][r];
  }
  __syncthreads();

#pragma unroll
  for (int g = 0; g < RT; ++g)
#pragma unroll
    for (int r = 0; r < 4; ++r) {
      const int row = g * 16 + lg * 4 + r;
      if (RV == MT || row < RV) {
        float ss = 0.f;
#pragma unroll
        for (int ww = 0; ww < 8; ++ww) ss += Ns[row * 8 + ww];
        const float scale = (RidC[row] < 0) ? 0.f : (1.f / fmaxf(sqrtf(ss), 1e-12f));
#pragma unroll
        for (int t = 0; t < 2; ++t)
          out[(size_t)(row0 + row) * D_OUT + (w * 2 + t) * 16 + lc] =
              (acc2[g][t][r] + bias2[t]) * scale;
      }
    }
}

// ----------------------------- fused main kernel --------------------------------
__global__ __launch_bounds__(THREADS, 1)
void tagproj_fused(const float* __restrict__ tab, const int* __restrict__ ids,
                   const bf16* __restrict__ w1f, const bf16* __restrict__ w2f,
                   const float* __restrict__ b1, const float* __restrict__ b2,
                   float* __restrict__ out) {
  extern __shared__ __align__(16) char lds[];
  bf16*  Ab  = (bf16*)(lds + OFF_A);
  bf16*  Hb  = (bf16*)(lds + OFF_H);
  float* Ns  = (float*)(lds + OFF_NS);
  int*   Rid = (int*)(lds + OFF_RID);

  const int tid = threadIdx.x;
  const int w   = tid >> 6;   // wave 0..7
  const int l   = tid & 63;
  const int lg  = l >> 4;     // k-group 0..3
  const int lc  = l & 15;     // row/col within 16-tile
  const int base = blockIdx.x * RPB;

  // prologue: serial gather of tile 0 into A[0]
  gather_rows(tab, ids, Ab, Rid, base, MT, MT, tid);

  // 4 full 48-row tiles (each prefetches the next) + 16-row tail (8 valid)
  process_tile<3, MT, true, MT, MT>(tab, ids, w1f, w2f, b1, b2, out,
      Ab, Hb, Ns, Rid, base, base + 48, 0, tid, w, l, lg, lc);
  process_tile<3, MT, true, MT, MT>(tab, ids, w1f, w2f, b1, b2, out,
      Ab, Hb, Ns, Rid, base + 48, base + 96, 1, tid, w, l, lg, lc);
  process_tile<3, MT, true, MT, MT>(tab, ids, w1f, w2f, b1, b2, out,
      Ab, Hb, Ns, Rid, base + 96, base + 144, 0, tid, w, l, lg, lc);
  process_tile<3, MT, true, 16, 8>(tab, ids, w1f, w2f, b1, b2, out,
      Ab, Hb, Ns, Rid, base + 144, base + 192, 1, tid, w, l, lg, lc);
  process_tile<1, 8, false, 0, 0>(tab, ids, w1f, w2f, b1, b2, out,
      Ab, Hb, Ns, Rid, base + 192, 0, 0, tid, w, l, lg, lc);
}

// --------------------------------- launcher ---------------------------------
extern "C" void kernel_launch(void* const* d_in, const int* in_sizes, int n_in,
                              void* d_out, int out_size, void* d_ws, size_t ws_size,
                              hipStream_t stream) {
  const float* tab = (const float*)d_in[0];
  const float* w1  = (const float*)d_in[1];
  const float* b1  = (const float*)d_in[2];
  const float* w2  = (const float*)d_in[3];
  const float* b2  = (const float*)d_in[4];
  const int*   ids = (const int*)d_in[5];
  float* out = (float*)d_out;

  bf16* w1f = (bf16*)d_ws;
  bf16* w2f = w1f + W1F_ELEMS;

  hipLaunchKernelGGL(prep_weights, dim3(384), dim3(256), 0, stream, w1, w2, w1f, w2f);

  (void)hipFuncSetAttribute(reinterpret_cast<const void*>(tagproj_fused),
                            hipFuncAttributeMaxDynamicSharedMemorySize, LDS_TOTAL);
  hipLaunchKernelGGL(tagproj_fused, dim3(NBLK), dim3(THREADS), LDS_TOTAL, stream,
                     tab, ids, w1f, w2f, b1, b2, out);
}